// Round 11
// baseline (26.472 us; speedup 1.0000x reference)
//
#include <hip/hip_runtime.h>
#include <hip/hip_fp16.h>

typedef _Float16 half8 __attribute__((ext_vector_type(8)));
typedef __attribute__((ext_vector_type(4))) float f32x4;

#define BATCH 64
#define L0 16384
#define L1 8192
#define NPG 4096
#define CF 8
#define H 64
#define CHUNK 128
#define NCHUNK 32
#define NCHUNKS_TOTAL 2048
#define GRID 1024
#define CPB 2

// ---- LDS arena (bytes) ----
// per-chunk (rewritten every iteration):
//   x  [0,2144)      alive A..B   (inside h1 region)
//   t1 [2144,6400)   alive B..C   (inside h1 region)
//   h1 [0,18720)     written D, read E
//   nd [18720,20832) written C, read D
//   red[20832,21856) phase E
// persistent across both chunks:
//   w2t [21856,30048), w1t [30048,34144), wct [34144,35168)
#define A_X    0
#define A_T1   2144
#define A_H1   0
#define A_ND   18720
#define A_RED  20832
#define A_W2T  21856
#define A_W1T  30048
#define A_WCT  34144
#define ARENA_BYTES 35168

__device__ __forceinline__ float disv(int p) {
    if (p < 0 || p >= NPG) return 0.f;
    if (p == 0 || p == NPG - 1) return 0.70710678118654752f;  // 1/sqrt(2)
    return 0.57735026918962576f;                              // 1/sqrt(3)
}
__device__ __forceinline__ unsigned packh2(float a, float b) {
    union { __half2 h; unsigned u; } cv;
    cv.h = __float22half2_rn(make_float2(a, b));
    return cv.u;
}
__device__ __forceinline__ unsigned short h1u(float f) {
    union { __half h; unsigned short u; } cv;
    cv.h = __float2half_rn(f);
    return cv.u;
}
__device__ __forceinline__ unsigned pkadd3(unsigned a, unsigned b, unsigned c) {
    union { unsigned u; __half2 h; } A, B, C, R;
    A.u = a; B.u = b; C.u = c;
    R.h = __hadd2(__hadd2(A.h, B.h), C.h);
    return R.u;
}
__device__ __forceinline__ float2 uph2(unsigned u) {
    union { unsigned uu; __half2 h; } cv; cv.uu = u;
    return __half22float2(cv.h);
}

// Fused pipeline; persistent blocks process 2 chunks each (one uniform round:
// 1024 blocks = 4/CU x 256 CUs). All weight tables persistent in LDS.
__global__ __launch_bounds__(256, 4) void k_fused(const float* __restrict__ x,
        const float* __restrict__ c1w, const float* __restrict__ c1b,
        const float* __restrict__ c2w, const float* __restrict__ c2b,
        const float* __restrict__ g1w, const float* __restrict__ g1b,
        const float* __restrict__ g2w, const float* __restrict__ g2b,
        float* __restrict__ partials) {
    __shared__ __align__(16) char arena[ARENA_BYTES];
    float*          x_l  = (float*)(arena + A_X);
    unsigned short* t1_l = (unsigned short*)(arena + A_T1);
    unsigned short* nd_l = (unsigned short*)(arena + A_ND);
    unsigned short* h1_l = (unsigned short*)(arena + A_H1);
    unsigned short* w2t  = (unsigned short*)(arena + A_W2T);
    unsigned short* w1t  = (unsigned short*)(arena + A_W1T);
    unsigned short* wct  = (unsigned short*)(arena + A_WCT);
    float*          red  = (float*)(arena + A_RED);
    unsigned* w2t32 = (unsigned*)w2t;
    unsigned* w1t32 = (unsigned*)w1t;

    const int tid = threadIdx.x;
    const int wave = tid >> 6;
    const int l = tid & 63;
    const int m = l & 15, q = l >> 4;
    const float T = 1.f / 3.f;
    const f32x4 z4 = {0.f, 0.f, 0.f, 0.f};

    // ---- prologue: build all weight tables once (persistent LDS) ----
    {
        uint4 z = {0u, 0u, 0u, 0u};
        *(uint4*)&w1t[tid * 8] = z;                    // 4096 B
        if (tid < 64) *(uint4*)&wct[tid * 8] = z;      // 1024 B
    }
    __syncthreads();   // zero-init visible before partial fills
    #pragma unroll
    for (int j = 0; j < 8; ++j) {                      // w2t, pair-packed
        int p = tid + 256 * j;
        int n = p & 63, rest = p >> 6;
        int i2 = rest & 3, qq = (rest >> 2) & 3, ks = rest >> 4;
        int e0 = (ks * 32 + qq * 8 + 2 * i2) * 64 + n;
        int lane = qq * 16 + (n & 15), ct = n >> 4;
        w2t32[((ct * 2 + ks) * 64 + lane) * 4 + i2] =
            packh2(g2w[e0] * T, g2w[e0 + 64] * T);
    }
    {   // w1t: lanes 0..15 only (qq=0), pairs
        int n = tid & 63, i2 = tid >> 6;
        int e0 = (2 * i2) * 64 + n;
        w1t32[((n >> 4) * 64 + (n & 15)) * 4 + i2] =
            packh2(g1w[e0] * T, g1w[e0 + 64] * T);
    }
    if (tid < 192) {                                   // c2w flat (192)
        int co = tid / 24, rem2 = tid % 24, ci = rem2 / 3, tap = rem2 % 3;
        wct[(tap * 16 + co) * 8 + ci] = h1u(c2w[tid]);
    }
    // (fills are covered by phase A's barrier)

    // ================= two chunks per block ================================
    for (int it = 0; it < CPB; ++it) {
        const int chunk = blockIdx.x + it * GRID;
        const int b = chunk >> 5, ch = chunk & 31;
        const int s = ch * CHUNK;
        const bool edgeblk = (ch == 0) || (ch == NCHUNK - 1);

        // ---- phase A: stage x cols [4s-11, 4s+524] ----
        {
            const float* xb = x + (size_t)b * L0;
            for (int c = tid; c < 536; c += 256) {
                int col = 4 * s - 11 + c;
                x_l[c] = (col >= 0 && col < L0) ? xb[col] : 0.f;
            }
        }
        __syncthreads();

        // ---- phase B: conv1+relu+pool -> t1 (fp16, rows 0..265) ----
        {
            int c0 = (tid & 3) * 2;
            float wA0 = c1w[c0 * 3], wB0 = c1w[c0 * 3 + 1], wC0 = c1w[c0 * 3 + 2];
            float wA1 = c1w[c0 * 3 + 3], wB1 = c1w[c0 * 3 + 4], wC1 = c1w[c0 * 3 + 5];
            float bb0 = c1b[c0], bb1 = c1b[c0 + 1];
            for (int v = tid; v < 266 * 4; v += 256) {
                int t = v >> 2;
                int g = 2 * s - 5 + t;
                unsigned o = 0;
                if (g >= 0 && g < L1) {
                    float a0 = x_l[2 * t], a1 = x_l[2 * t + 1];
                    float a2 = x_l[2 * t + 2], a3 = x_l[2 * t + 3];
                    float y00 = bb0 + wA0 * a0 + wB0 * a1 + wC0 * a2;
                    float y01 = bb0 + wA0 * a1 + wB0 * a2 + wC0 * a3;
                    float y10 = bb1 + wA1 * a0 + wB1 * a1 + wC1 * a2;
                    float y11 = bb1 + wA1 * a1 + wB1 * a2 + wC1 * a3;
                    o = packh2(fmaxf(fmaxf(y00, y01), 0.f),
                               fmaxf(fmaxf(y10, y11), 0.f));
                }
                *(unsigned*)&t1_l[t * 8 + c0] = o;
            }
        }
        __syncthreads();

        // ---- phase C: conv2 via MFMA (+bias+relu+pool) -> nd (fp16) ----
        {
            half8 wcfr = ((const half8*)wct)[l];
            float bb2 = (m < CF) ? c2b[m] : 0.f;
            for (int rt = wave; rt < 17; rt += 4) {
                int rr = rt * 16 + m + q;
                rr = rr > 265 ? 265 : rr;
                half8 a = *(const half8*)&t1_l[rr * 8];
                f32x4 c = __builtin_amdgcn_mfma_f32_16x16x32_f16(a, wcfr, z4, 0, 0, 0);
                if (m < CF) {
                    int n0 = rt * 8 + q * 2;
                    if (n0 < 132)
                        nd_l[n0 * 8 + m] = h1u(fmaxf(fmaxf(c[0], c[1]) + bb2, 0.f));
                    if (n0 + 1 < 132)
                        nd_l[(n0 + 1) * 8 + m] = h1u(fmaxf(fmaxf(c[2], c[3]) + bb2, 0.f));
                }
            }
        }
        __syncthreads();

        // ---- phase D: GCN1 MFMA swapped (D = W1^T x stencil^T) ----
        {
            half8 w1fr[4];
            float4 b1v[4];
            #pragma unroll
            for (int ct = 0; ct < 4; ++ct) {
                w1fr[ct] = ((const half8*)w1t)[ct * 64 + l];
                b1v[ct] = *(const float4*)&g1b[ct * 16 + q * 4];
            }
            for (int rt = wave; rt < 9; rt += 4) {
                int rc = rt * 16 + m;
                int rcc = rc > 129 ? 129 : rc;
                uint4 RL = *(const uint4*)&nd_l[rcc * 8];
                uint4 RM = *(const uint4*)&nd_l[(rcc + 1) * 8];
                uint4 RH = *(const uint4*)&nd_l[(rcc + 2) * 8];
                union { unsigned u[4]; half8 h8; } sf;
                if (!edgeblk) {
                    sf.u[0] = pkadd3(RL.x, RM.x, RH.x);
                    sf.u[1] = pkadd3(RL.y, RM.y, RH.y);
                    sf.u[2] = pkadd3(RL.z, RM.z, RH.z);
                    sf.u[3] = pkadd3(RL.w, RM.w, RH.w);
                } else {
                    int p = s - 1 + rcc;
                    float dc = disv(p);
                    float cm_ = 3.f * dc * dc;
                    float cl_ = 3.f * dc * disv(p - 1);
                    float cr_ = 3.f * dc * disv(p + 1);
                    #define SFE(e, UL, UM, UH)                                    \
                      { float2 Lf = uph2(UL), Mf = uph2(UM), Hf = uph2(UH);       \
                        sf.u[e] = packh2(cm_*Mf.x + cl_*Lf.x + cr_*Hf.x,          \
                                         cm_*Mf.y + cl_*Lf.y + cr_*Hf.y); }
                    SFE(0, RL.x, RM.x, RH.x)
                    SFE(1, RL.y, RM.y, RH.y)
                    SFE(2, RL.z, RM.z, RH.z)
                    SFE(3, RL.w, RM.w, RH.w)
                    #undef SFE
                }
                bool wok = rc < 130;
                #pragma unroll
                for (int ct = 0; ct < 4; ++ct) {
                    f32x4 c = __builtin_amdgcn_mfma_f32_16x16x32_f16(
                        w1fr[ct], sf.h8, z4, 0, 0, 0);
                    if (wok) {
                        unsigned p01 = packh2(fmaxf(c[0] + b1v[ct].x, 0.f),
                                              fmaxf(c[1] + b1v[ct].y, 0.f));
                        unsigned p23 = packh2(fmaxf(c[2] + b1v[ct].z, 0.f),
                                              fmaxf(c[3] + b1v[ct].w, 0.f));
                        *(uint2*)&h1_l[rc * 72 + ct * 16 + q * 4] =
                            make_uint2(p01, p23);
                    }
                }
            }
        }
        __syncthreads();

        // ---- phase E: GCN2 MFMA (A2 = pk-add of 3 h1 rows) + pool ----
        {
            half8 w2fr[4][2];
            float b2v[4];
            #pragma unroll
            for (int ct = 0; ct < 4; ++ct) {
                w2fr[ct][0] = ((const half8*)w2t)[(ct * 2 + 0) * 64 + l];
                w2fr[ct][1] = ((const half8*)w2t)[(ct * 2 + 1) * 64 + l];
                b2v[ct] = g2b[ct * 16 + m];
            }
            float pool_acc[4] = {0.f, 0.f, 0.f, 0.f};
            for (int rt = wave; rt < 8; rt += 4) {
                f32x4 accg[4] = {z4, z4, z4, z4};
                int r0 = rt * 16 + m;
                float cl_ = 0.f, cm_ = 0.f, cr_ = 0.f;
                if (edgeblk) {
                    int p = s + r0;
                    float dcp = disv(p);
                    cm_ = 3.f * dcp * dcp;
                    cl_ = 3.f * dcp * disv(p - 1);
                    cr_ = 3.f * dcp * disv(p + 1);
                }
                #pragma unroll
                for (int ks = 0; ks < 2; ++ks) {
                    int koff = ks * 32 + q * 8;
                    uint4 lo = *(const uint4*)&h1_l[r0 * 72 + koff];
                    uint4 mi = *(const uint4*)&h1_l[(r0 + 1) * 72 + koff];
                    uint4 hi = *(const uint4*)&h1_l[(r0 + 2) * 72 + koff];
                    union { unsigned u[4]; half8 h8; } a2;
                    if (!edgeblk) {
                        a2.u[0] = pkadd3(lo.x, mi.x, hi.x);
                        a2.u[1] = pkadd3(lo.y, mi.y, hi.y);
                        a2.u[2] = pkadd3(lo.z, mi.z, hi.z);
                        a2.u[3] = pkadd3(lo.w, mi.w, hi.w);
                    } else {
                        #define A2E(e, UL, UM, UH)                                \
                          { float2 Lf = uph2(UL), Mf = uph2(UM), Hf = uph2(UH);   \
                            a2.u[e] = packh2(cm_*Mf.x + cl_*Lf.x + cr_*Hf.x,      \
                                             cm_*Mf.y + cl_*Lf.y + cr_*Hf.y); }
                        A2E(0, lo.x, mi.x, hi.x)
                        A2E(1, lo.y, mi.y, hi.y)
                        A2E(2, lo.z, mi.z, hi.z)
                        A2E(3, lo.w, mi.w, hi.w)
                        #undef A2E
                    }
                    #pragma unroll
                    for (int ct = 0; ct < 4; ++ct)
                        accg[ct] = __builtin_amdgcn_mfma_f32_16x16x32_f16(
                            a2.h8, w2fr[ct][ks], accg[ct], 0, 0, 0);
                }
                #pragma unroll
                for (int ct = 0; ct < 4; ++ct)
                    #pragma unroll
                    for (int i = 0; i < 4; ++i)
                        pool_acc[ct] += fmaxf(accg[ct][i] + b2v[ct], 0.f);
            }
            #pragma unroll
            for (int ct = 0; ct < 4; ++ct) {
                float v = pool_acc[ct];
                v += __shfl_xor(v, 16);
                v += __shfl_xor(v, 32);
                if (q == 0) red[wave * 64 + ct * 16 + m] = v;
            }
        }
        __syncthreads();
        if (tid < H) {
            partials[(size_t)chunk * H + tid] = red[tid] + red[64 + tid]
                                              + red[128 + tid] + red[192 + tid];
        }
        // next chunk's phase A barrier orders x_l writes vs this chunk's h1/red reads
    }
}

// per-graph reduce over chunks + mean + fc
__global__ __launch_bounds__(256) void k_final(const float* __restrict__ partials,
        const float* __restrict__ fcw, const float* __restrict__ fcb,
        float* __restrict__ out) {
    __shared__ float red[4][H];
    __shared__ float pool_l[H];
    int bgr = blockIdx.x;
    int tid = threadIdx.x;
    int g = tid >> 6, j = tid & 63;
    float acc = 0.f;
    for (int c = g; c < NCHUNK; c += 4)
        acc += partials[((size_t)bgr * NCHUNK + c) * H + j];
    red[g][j] = acc;
    __syncthreads();
    if (tid < H)
        pool_l[j] = (red[0][j] + red[1][j] + red[2][j] + red[3][j]) * (1.f / NPG);
    __syncthreads();
    if (tid < 2) {
        float o = fcb[tid];
        for (int k = 0; k < H; ++k) o += pool_l[k] * fcw[k * 2 + tid];
        out[bgr * 2 + tid] = o;
    }
}

extern "C" void kernel_launch(void* const* d_in, const int* in_sizes, int n_in,
                              void* d_out, int out_size, void* d_ws, size_t ws_size,
                              hipStream_t stream) {
    (void)in_sizes; (void)n_in; (void)out_size; (void)ws_size;
    const float* x   = (const float*)d_in[0];
    const float* c1w = (const float*)d_in[2];
    const float* c1b = (const float*)d_in[3];
    const float* c2w = (const float*)d_in[4];
    const float* c2b = (const float*)d_in[5];
    const float* g1w = (const float*)d_in[6];
    const float* g1b = (const float*)d_in[7];
    const float* g2w = (const float*)d_in[8];
    const float* g2b = (const float*)d_in[9];
    const float* fcw = (const float*)d_in[10];
    const float* fcb = (const float*)d_in[11];
    float* out = (float*)d_out;

    float* partials = (float*)d_ws;     // [2048][64] f32 = 512 KB

    k_fused<<<GRID, 256, 0, stream>>>(x, c1w, c1b, c2w, c2b,
                                      g1w, g1b, g2w, g2b, partials);
    k_final<<<BATCH, 256, 0, stream>>>(partials, fcw, fcb, out);
}

// Round 12
// 24.860 us; speedup vs baseline: 1.0648x; 1.0648x over previous
//
#include <hip/hip_runtime.h>
#include <hip/hip_fp16.h>

typedef _Float16 half8 __attribute__((ext_vector_type(8)));
typedef __attribute__((ext_vector_type(4))) float f32x4;

#define BATCH 64
#define L0 16384
#define L1 8192
#define NPG 4096
#define CF 8
#define H 64
#define CHUNK 128
#define NCHUNK 32
#define NCHUNKS_TOTAL 2048

// ---- LDS arena (bytes), time-disjoint aliasing (R10 layout minus x) ----
//  t1  [0,4256)      alive conv..C   (inside h1 region)
//  w1t [11008,15104) alive pro..C-end (regs loaded before C->D barrier)
//  wct [15104,16128) alive pro..C
//  h1  [0,18720)     written D, read E
//  nd  [18720,20832) written C, read D
//  red [20832,21856) phase E
//  w2t [21856,30048) persistent
#define A_T1   0
#define P_W1T  11008
#define P_WCT  15104
#define A_H1   0
#define A_ND   18720
#define A_RED  20832
#define A_W2T  21856
#define ARENA_BYTES 30048

__device__ __forceinline__ float disv(int p) {
    if (p < 0 || p >= NPG) return 0.f;
    if (p == 0 || p == NPG - 1) return 0.70710678118654752f;  // 1/sqrt(2)
    return 0.57735026918962576f;                              // 1/sqrt(3)
}
__device__ __forceinline__ unsigned packh2(float a, float b) {
    union { __half2 h; unsigned u; } cv;
    cv.h = __float22half2_rn(make_float2(a, b));
    return cv.u;
}
__device__ __forceinline__ unsigned short h1u(float f) {
    union { __half h; unsigned short u; } cv;
    cv.h = __float2half_rn(f);
    return cv.u;
}
__device__ __forceinline__ unsigned pkadd3(unsigned a, unsigned b, unsigned c) {
    union { unsigned u; __half2 h; } A, B, C, R;
    A.u = a; B.u = b; C.u = c;
    R.h = __hadd2(__hadd2(A.h, B.h), C.h);
    return R.u;
}
__device__ __forceinline__ float2 uph2(unsigned u) {
    union { unsigned uu; __half2 h; } cv; cv.uu = u;
    return __half22float2(cv.h);
}

// Fused: conv1(global-direct)+pool -> conv2(MFMA)+pool -> GCN1(MFMA swapped)
// -> GCN2(MFMA) -> mean-pool partials. One block per 128-node chunk.
__global__ __launch_bounds__(256, 5) void k_fused(const float* __restrict__ x,
        const float* __restrict__ c1w, const float* __restrict__ c1b,
        const float* __restrict__ c2w, const float* __restrict__ c2b,
        const float* __restrict__ g1w, const float* __restrict__ g1b,
        const float* __restrict__ g2w, const float* __restrict__ g2b,
        float* __restrict__ partials) {
    __shared__ __align__(16) char arena[ARENA_BYTES];
    unsigned short* t1_l = (unsigned short*)(arena + A_T1);
    unsigned short* nd_l = (unsigned short*)(arena + A_ND);
    unsigned short* h1_l = (unsigned short*)(arena + A_H1);
    unsigned short* w2t  = (unsigned short*)(arena + A_W2T);
    unsigned short* w1t  = (unsigned short*)(arena + P_W1T);
    unsigned short* wct  = (unsigned short*)(arena + P_WCT);
    float*          red  = (float*)(arena + A_RED);
    unsigned* w2t32 = (unsigned*)w2t;
    unsigned* w1t32 = (unsigned*)w1t;

    const int tid = threadIdx.x;
    const int wave = tid >> 6;
    const int l = tid & 63;
    const int m = l & 15, q = l >> 4;
    const float T = 1.f / 3.f;
    const f32x4 z4 = {0.f, 0.f, 0.f, 0.f};

    const int chunk = blockIdx.x;
    const int b = chunk >> 5, ch = chunk & 31;
    const int s = ch * CHUNK;
    const bool edgeblk = (ch == 0) || (ch == NCHUNK - 1);

    // ---- zero-init partially-filled tables ----
    {
        uint4 z = {0u, 0u, 0u, 0u};
        *(uint4*)&w1t[tid * 8] = z;                    // 4096 B
        if (tid < 64) *(uint4*)&wct[tid * 8] = z;      // 1024 B
    }
    __syncthreads();

    // ==== merged region: weight-table fills + conv1 (all independent) ====
    #pragma unroll
    for (int j = 0; j < 8; ++j) {                      // w2t, pair-packed
        int p = tid + 256 * j;
        int n = p & 63, rest = p >> 6;
        int i2 = rest & 3, qq = (rest >> 2) & 3, ks = rest >> 4;
        int e0 = (ks * 32 + qq * 8 + 2 * i2) * 64 + n;
        int lane = qq * 16 + (n & 15), ct = n >> 4;
        w2t32[((ct * 2 + ks) * 64 + lane) * 4 + i2] =
            packh2(g2w[e0] * T, g2w[e0 + 64] * T);
    }
    {   // w1t: lanes 0..15 only (qq=0), pairs
        int n = tid & 63, i2 = tid >> 6;
        int e0 = (2 * i2) * 64 + n;
        w1t32[((n >> 4) * 64 + (n & 15)) * 4 + i2] =
            packh2(g1w[e0] * T, g1w[e0 + 64] * T);
    }
    if (tid < 192) {                                   // c2w flat (192)
        int co = tid / 24, rem2 = tid % 24, ci = rem2 / 3, tap = rem2 % 3;
        wct[(tap * 16 + co) * 8 + ci] = h1u(c2w[tid]);
    }
    // conv1+relu+pool -> t1 (fp16), one row per thread, direct global reads
    {
        const float* xb = x + (size_t)b * L0;
        float wA[8], wB[8], wC[8], bb[8];
        #pragma unroll
        for (int c = 0; c < 8; ++c) {
            wA[c] = c1w[3 * c]; wB[c] = c1w[3 * c + 1]; wC[c] = c1w[3 * c + 2];
            bb[c] = c1b[c];
        }
        #pragma unroll
        for (int it2 = 0; it2 < 2; ++it2) {
            int t = tid + it2 * 256;
            if (t < 266) {
                uint4 o = {0u, 0u, 0u, 0u};
                int g = 2 * s - 5 + t;
                if (g >= 0 && g < L1) {
                    int col = 2 * g - 1;
                    float a0 = (col >= 0) ? xb[col] : 0.f;
                    float a1 = xb[col + 1];
                    float a2 = xb[col + 2];
                    float a3 = (col + 3 < L0) ? xb[col + 3] : 0.f;
                    unsigned pw[4];
                    #pragma unroll
                    for (int c = 0; c < 4; ++c) {
                        int c0 = 2 * c, c1_ = 2 * c + 1;
                        float y00 = bb[c0] + wA[c0] * a0 + wB[c0] * a1 + wC[c0] * a2;
                        float y01 = bb[c0] + wA[c0] * a1 + wB[c0] * a2 + wC[c0] * a3;
                        float y10 = bb[c1_] + wA[c1_] * a0 + wB[c1_] * a1 + wC[c1_] * a2;
                        float y11 = bb[c1_] + wA[c1_] * a1 + wB[c1_] * a2 + wC[c1_] * a3;
                        pw[c] = packh2(fmaxf(fmaxf(y00, y01), 0.f),
                                       fmaxf(fmaxf(y10, y11), 0.f));
                    }
                    o.x = pw[0]; o.y = pw[1]; o.z = pw[2]; o.w = pw[3];
                }
                *(uint4*)&t1_l[t * 8] = o;
            }
        }
    }
    __syncthreads();

    // ---- phase C: conv2 via MFMA (+bias+relu+pool) -> nd (fp16) ----
    half8 w1fr[4];
    {
        half8 wcfr = ((const half8*)wct)[l];
        float bb2 = (m < CF) ? c2b[m] : 0.f;
        auto convC = [&](int rt) {
            int rr = rt * 16 + m + q;
            rr = rr > 265 ? 265 : rr;
            half8 a = *(const half8*)&t1_l[rr * 8];
            f32x4 c = __builtin_amdgcn_mfma_f32_16x16x32_f16(a, wcfr, z4, 0, 0, 0);
            if (m < CF) {
                int n0 = rt * 8 + q * 2;
                if (n0 < 132)
                    nd_l[n0 * 8 + m] = h1u(fmaxf(fmaxf(c[0], c[1]) + bb2, 0.f));
                if (n0 + 1 < 132)
                    nd_l[(n0 + 1) * 8 + m] = h1u(fmaxf(fmaxf(c[2], c[3]) + bb2, 0.f));
            }
        };
        convC(wave); convC(wave + 4); convC(wave + 8); convC(wave + 12);
        if (wave == 0) convC(16);
        // load w1 frags BEFORE the barrier (w1t region overwritten by h1 in D)
        #pragma unroll
        for (int ct = 0; ct < 4; ++ct)
            w1fr[ct] = ((const half8*)w1t)[ct * 64 + l];
    }
    __syncthreads();

    // ---- phase D: GCN1 MFMA swapped (D = W1^T x stencil^T) ----
    {
        float4 b1v[4];
        #pragma unroll
        for (int ct = 0; ct < 4; ++ct)
            b1v[ct] = *(const float4*)&g1b[ct * 16 + q * 4];
        auto doD = [&](int rt) {
            int rc = rt * 16 + m;
            int rcc = rc > 129 ? 129 : rc;
            uint4 RL = *(const uint4*)&nd_l[rcc * 8];
            uint4 RM = *(const uint4*)&nd_l[(rcc + 1) * 8];
            uint4 RH = *(const uint4*)&nd_l[(rcc + 2) * 8];
            union { unsigned u[4]; half8 h8; } sf;
            if (!edgeblk) {
                sf.u[0] = pkadd3(RL.x, RM.x, RH.x);
                sf.u[1] = pkadd3(RL.y, RM.y, RH.y);
                sf.u[2] = pkadd3(RL.z, RM.z, RH.z);
                sf.u[3] = pkadd3(RL.w, RM.w, RH.w);
            } else {
                int p = s - 1 + rcc;
                float dc = disv(p);
                float cm_ = 3.f * dc * dc;
                float cl_ = 3.f * dc * disv(p - 1);
                float cr_ = 3.f * dc * disv(p + 1);
                #define SFE(e, UL, UM, UH)                                    \
                  { float2 Lf = uph2(UL), Mf = uph2(UM), Hf = uph2(UH);       \
                    sf.u[e] = packh2(cm_*Mf.x + cl_*Lf.x + cr_*Hf.x,          \
                                     cm_*Mf.y + cl_*Lf.y + cr_*Hf.y); }
                SFE(0, RL.x, RM.x, RH.x)
                SFE(1, RL.y, RM.y, RH.y)
                SFE(2, RL.z, RM.z, RH.z)
                SFE(3, RL.w, RM.w, RH.w)
                #undef SFE
            }
            bool wok = rc < 130;
            #pragma unroll
            for (int ct = 0; ct < 4; ++ct) {
                f32x4 c = __builtin_amdgcn_mfma_f32_16x16x32_f16(
                    w1fr[ct], sf.h8, z4, 0, 0, 0);
                if (wok) {
                    unsigned p01 = packh2(fmaxf(c[0] + b1v[ct].x, 0.f),
                                          fmaxf(c[1] + b1v[ct].y, 0.f));
                    unsigned p23 = packh2(fmaxf(c[2] + b1v[ct].z, 0.f),
                                          fmaxf(c[3] + b1v[ct].w, 0.f));
                    *(uint2*)&h1_l[rc * 72 + ct * 16 + q * 4] =
                        make_uint2(p01, p23);
                }
            }
        };
        doD(wave); doD(wave + 4);
        if (wave == 0) doD(8);
    }
    __syncthreads();

    // ---- phase E: GCN2 MFMA (A2 = pk-add of 3 h1 rows) + pool ----
    {
        half8 w2fr[4][2];
        float b2v[4];
        #pragma unroll
        for (int ct = 0; ct < 4; ++ct) {
            w2fr[ct][0] = ((const half8*)w2t)[(ct * 2 + 0) * 64 + l];
            w2fr[ct][1] = ((const half8*)w2t)[(ct * 2 + 1) * 64 + l];
            b2v[ct] = g2b[ct * 16 + m];
        }
        float pool_acc[4] = {0.f, 0.f, 0.f, 0.f};
        auto doE = [&](int rt) {
            f32x4 accg[4] = {z4, z4, z4, z4};
            int r0 = rt * 16 + m;
            float cl_ = 0.f, cm_ = 0.f, cr_ = 0.f;
            if (edgeblk) {
                int p = s + r0;
                float dcp = disv(p);
                cm_ = 3.f * dcp * dcp;
                cl_ = 3.f * dcp * disv(p - 1);
                cr_ = 3.f * dcp * disv(p + 1);
            }
            #pragma unroll
            for (int ks = 0; ks < 2; ++ks) {
                int koff = ks * 32 + q * 8;
                uint4 lo = *(const uint4*)&h1_l[r0 * 72 + koff];
                uint4 mi = *(const uint4*)&h1_l[(r0 + 1) * 72 + koff];
                uint4 hi = *(const uint4*)&h1_l[(r0 + 2) * 72 + koff];
                union { unsigned u[4]; half8 h8; } a2;
                if (!edgeblk) {
                    a2.u[0] = pkadd3(lo.x, mi.x, hi.x);
                    a2.u[1] = pkadd3(lo.y, mi.y, hi.y);
                    a2.u[2] = pkadd3(lo.z, mi.z, hi.z);
                    a2.u[3] = pkadd3(lo.w, mi.w, hi.w);
                } else {
                    #define A2E(e, UL, UM, UH)                                \
                      { float2 Lf = uph2(UL), Mf = uph2(UM), Hf = uph2(UH);   \
                        a2.u[e] = packh2(cm_*Mf.x + cl_*Lf.x + cr_*Hf.x,      \
                                         cm_*Mf.y + cl_*Lf.y + cr_*Hf.y); }
                    A2E(0, lo.x, mi.x, hi.x)
                    A2E(1, lo.y, mi.y, hi.y)
                    A2E(2, lo.z, mi.z, hi.z)
                    A2E(3, lo.w, mi.w, hi.w)
                    #undef A2E
                }
                #pragma unroll
                for (int ct = 0; ct < 4; ++ct)
                    accg[ct] = __builtin_amdgcn_mfma_f32_16x16x32_f16(
                        a2.h8, w2fr[ct][ks], accg[ct], 0, 0, 0);
            }
            #pragma unroll
            for (int ct = 0; ct < 4; ++ct)
                #pragma unroll
                for (int i = 0; i < 4; ++i)
                    pool_acc[ct] += fmaxf(accg[ct][i] + b2v[ct], 0.f);
        };
        doE(wave); doE(wave + 4);
        #pragma unroll
        for (int ct = 0; ct < 4; ++ct) {
            float v = pool_acc[ct];
            v += __shfl_xor(v, 16);
            v += __shfl_xor(v, 32);
            if (q == 0) red[wave * 64 + ct * 16 + m] = v;
        }
    }
    __syncthreads();
    if (tid < H) {
        partials[(size_t)chunk * H + tid] = red[tid] + red[64 + tid]
                                          + red[128 + tid] + red[192 + tid];
    }
}

// per-graph reduce over chunks + mean + fc
__global__ __launch_bounds__(256) void k_final(const float* __restrict__ partials,
        const float* __restrict__ fcw, const float* __restrict__ fcb,
        float* __restrict__ out) {
    __shared__ float red[4][H];
    __shared__ float pool_l[H];
    int bgr = blockIdx.x;
    int tid = threadIdx.x;
    int g = tid >> 6, j = tid & 63;
    float acc = 0.f;
    for (int c = g; c < NCHUNK; c += 4)
        acc += partials[((size_t)bgr * NCHUNK + c) * H + j];
    red[g][j] = acc;
    __syncthreads();
    if (tid < H)
        pool_l[j] = (red[0][j] + red[1][j] + red[2][j] + red[3][j]) * (1.f / NPG);
    __syncthreads();
    if (tid < 2) {
        float o = fcb[tid];
        for (int k = 0; k < H; ++k) o += pool_l[k] * fcw[k * 2 + tid];
        out[bgr * 2 + tid] = o;
    }
}

extern "C" void kernel_launch(void* const* d_in, const int* in_sizes, int n_in,
                              void* d_out, int out_size, void* d_ws, size_t ws_size,
                              hipStream_t stream) {
    (void)in_sizes; (void)n_in; (void)out_size; (void)ws_size;
    const float* x   = (const float*)d_in[0];
    const float* c1w = (const float*)d_in[2];
    const float* c1b = (const float*)d_in[3];
    const float* c2w = (const float*)d_in[4];
    const float* c2b = (const float*)d_in[5];
    const float* g1w = (const float*)d_in[6];
    const float* g1b = (const float*)d_in[7];
    const float* g2w = (const float*)d_in[8];
    const float* g2b = (const float*)d_in[9];
    const float* fcw = (const float*)d_in[10];
    const float* fcb = (const float*)d_in[11];
    float* out = (float*)d_out;

    float* partials = (float*)d_ws;     // [2048][64] f32 = 512 KB

    k_fused<<<NCHUNKS_TOTAL, 256, 0, stream>>>(x, c1w, c1b, c2w, c2b,
                                               g1w, g1b, g2w, g2b, partials);
    k_final<<<BATCH, 256, 0, stream>>>(partials, fcw, fcb, out);
}